// Round 1
// baseline (399.695 us; speedup 1.0000x reference)
//
#include <hip/hip_runtime.h>

#define BB 4
#define NT 256
#define NZ 384
#define NX 384
#define NREC 128
#define NZX (NZ*NX)        // 147456
#define BNZX (BB*NZX)      // 589824
#define DT 0.001f
#define INV_DH2 0.01f      // 1/(10*10)

#define TILE 32            // interior tile edge
#define HALO 16            // halo width = steps per exchange window
#define REGN 64            // TILE + 2*HALO (8 waves x 8 rows, 64 lanes = cols)
#define NTD  12            // tiles per dimension (384/32)
#define TPB  144           // tiles per batch (12*12)
#define NBLK 576           // 12x12 tiles x 4 batches (~2.25 blocks/CU, cap 3)
#define NTHR 512           // 8 waves: wave w owns rows 8w..8w+7, lane = col
#define FSTRIDE 16         // flag spread (64 B) -> no line sharing

__global__ void wave_init(unsigned* flags) {
    int i = blockIdx.x * blockDim.x + threadIdx.x;
    if (i < NBLK * FSTRIDE) flags[i] = 0u;
}

__device__ inline float dpp_shl1(float v) {
    return __int_as_float(__builtin_amdgcn_update_dpp(
        0, __float_as_int(v), 0x130 /*WAVE_SHL1*/, 0xf, 0xf, true));
}
__device__ inline float dpp_shr1(float v) {
    return __int_as_float(__builtin_amdgcn_update_dpp(
        0, __float_as_int(v), 0x138 /*WAVE_SHR1*/, 0xf, 0xf, true));
}

// (cur,prv) packed into one 8B word: halves scattered LLC ops per exchange.
__device__ inline unsigned long long pk2(float a, float b) {
    union { float f[2]; unsigned long long u; } t; t.f[0] = a; t.f[1] = b; return t.u;
}
__device__ inline void upk2(unsigned long long v, float& a, float& b) {
    union { unsigned long long u; float f[2]; } t; t.u = v; a = t.f[0]; b = t.f[1];
}

// Neighbor-only sync: arrival = plain agent-scope store to own spread flag;
// wait = wave 0, lanes 0..7 poll the <=8 neighbor flags (others poll own).
// 2-deep ping-pong frames are safe under neighbor-only sync: B overwrites
// frame k-2 only after observing neighbor flags >= k-1 (exchange k-1), which
// implies neighbors finished reading frame k-2. No global coupling.
__device__ inline void grid_sync(unsigned* flags, unsigned gen, int nbId) {
    __syncthreads();   // drains vmcnt(0): frame stores at LLC before flag store
    if (threadIdx.x < 64) {
        if (threadIdx.x == 0)
            __hip_atomic_store(&flags[blockIdx.x * FSTRIDE], gen,
                               __ATOMIC_RELAXED, __HIP_MEMORY_SCOPE_AGENT);
        for (;;) {
            unsigned f = __hip_atomic_load(&flags[nbId * FSTRIDE],
                             __ATOMIC_RELAXED, __HIP_MEMORY_SCOPE_AGENT);
            if (__all(f >= gen)) break;
            __builtin_amdgcn_s_sleep(1);
        }
    }
    __syncthreads();
}

__global__ __launch_bounds__(NTHR, 6)   // 6 waves/EU = 3 blocks/CU guaranteed
void wave_tiled(float* __restrict__ ws, const float* __restrict__ vp,
                const float* __restrict__ x,
                const int* __restrict__ src_y, const int* __restrict__ src_x,
                const int* __restrict__ rec_y, const int* __restrict__ rec_x,
                float* __restrict__ y) {
    __shared__ float bnd[2][16][REGN];   // [parity][2*wave+{top,bot}][col]
    __shared__ float recBuf[NREC][8];    // receiver samples, flushed per 8 steps
    __shared__ float xs[NT];             // this batch's source trace
    __shared__ int recLoc[NREC], recOut[NREC];
    __shared__ int recCnt;

    unsigned* flags = (unsigned*)(ws + 4*BNZX);

    const int tid = threadIdx.x;
    const int col = tid & 63;
    const int w   = tid >> 6;
    const int r0  = w << 3;
    const int blk = blockIdx.x;
    const int b   = blk / TPB;
    const int rem = blk - b*TPB;
    const int tz  = rem / NTD;
    const int tx  = rem - tz*NTD;
    const int oz = tz*TILE - HALO, ox = tx*TILE - HALO;
    const int gx = ox + col;
    const int sy = src_y[b], sx = src_x[b];

    if (tid == 0) recCnt = 0;
    for (int k = tid; k < 16*REGN; k += NTHR) ((float*)bnd[0])[k] = 0.f;
    for (int k = tid; k < NT; k += NTHR) xs[k] = x[b*NT + k];
    __syncthreads();
    for (int r = tid; r < NREC; r += NTHR) {
        int ry = rec_y[r], rx = rec_x[r];
        if (ry/TILE == tz && rx/TILE == tx) {
            int p = atomicAdd(&recCnt, 1);
            recLoc[p] = ((ry - oz) << 6) | (rx - ox);
            recOut[p] = b*NREC + r;
        }
    }
    __syncthreads();

    // per-thread receiver ownership cache (cap 4, LDS-loop fallback)
    int myN = 0, myM[4], myP[4];
    bool ovf = false;
    for (int p = 0; p < recCnt; ++p) {
        int rl = recLoc[p];
        if ((rl & 63) == col) {
            int rm = (rl >> 6) - r0;
            if ((unsigned)rm < 8u) {
                if (myN < 4) { myM[myN] = rm; myP[myN] = p; ++myN; }
                else ovf = true;
            }
        }
    }

    // neighbor ids for the sync (lanes 0..7 of wave 0; others self)
    int nbId = blk;
    if (tid < 8) {
        int d = tid + (tid >= 4);            // 0..8 skipping center 4
        int nz2 = tz + d/3 - 1, nx2 = tx + d%3 - 1;
        if ((unsigned)nz2 < (unsigned)NTD && (unsigned)nx2 < (unsigned)NTD)
            nbId = b*TPB + nz2*NTD + nx2;
    }

    // per-thread column state: 8 rows in registers
    float cur[8], prv[8], c2i[8];
    #pragma unroll
    for (int m = 0; m < 8; ++m) {
        cur[m] = 0.f; prv[m] = 0.f;
        const int gz = oz + r0 + m;
        const bool inner = (gz > 0 && gz < NZ-1 && gx > 0 && gx < NX-1);
        const float v = inner ? vp[gz*NX + gx] * DT : 0.f;
        c2i[m] = v * v * INV_DH2;    // 0 at edges -> lap auto-masked
    }
    const bool srcCol = (gx == sx);
    const int  srcM   = sy - oz - r0;
    const int  iuUp   = (2*w-1 < 0) ? 0 : 2*w-1;
    const int  iuDn   = (2*w+2 > 15) ? 15 : 2*w+2;
    // light-cone skip: waves 0/7 hold rows entirely outside the validity cone
    // for window-step k>=7 (validity after k+1 steps is rows [k+1, 63-k));
    // their outputs are discarded by the halo reload, and stale bnd values
    // they'd have produced only feed other invalid cells.
    const bool edgeW = (w == 0) || (w == 7);
    __syncthreads();

    #pragma unroll 1
    for (int t = 0; t < NT; ++t) {
        const int pr = t & 1, pw = pr ^ 1;
        const bool act = !(edgeW && (t & 15) >= 7);

        if (act) {
            const float upB = bnd[pr][iuUp][col];
            const float dnB = bnd[pr][iuDn][col];

            float hn[8];
            #pragma unroll
            for (int m = 0; m < 8; ++m) {
                const float ce = cur[m];
                const float up = (m == 0) ? upB : cur[m-1];
                const float dn = (m == 7) ? dnB : cur[m+1];
                const float lf = dpp_shl1(ce);
                const float rt = dpp_shr1(ce);
                const float s  = (up + dn) + (lf + rt);
                hn[m] = fmaf(2.f, ce, -prv[m]) + c2i[m] * fmaf(-4.f, ce, s);
            }
            #pragma unroll
            for (int m = 0; m < 8; ++m) { prv[m] = cur[m]; cur[m] = hn[m]; }

            if (srcCol && (unsigned)srcM < 8u) {
                const float xv = xs[t];
                #pragma unroll
                for (int m = 0; m < 8; ++m) if (m == srcM) cur[m] += xv;
            }
            // receiver sampling -> LDS buffer (no global ops in the step loop)
            {
                const int s2 = t & 7;
                if (ovf) {
                    for (int p = 0; p < recCnt; ++p) {
                        int rl = recLoc[p];
                        if ((rl & 63) == col) {
                            int rm = (rl >> 6) - r0;
                            if ((unsigned)rm < 8u) {
                                float v = cur[0];
                                #pragma unroll
                                for (int m = 1; m < 8; ++m) if (rm == m) v = cur[m];
                                recBuf[p][s2] = v;
                            }
                        }
                    }
                } else {
                    #pragma unroll
                    for (int k = 0; k < 4; ++k) {
                        if (k < myN) {
                            float v = cur[0];
                            #pragma unroll
                            for (int m = 1; m < 8; ++m) if (myM[k] == m) v = cur[m];
                            recBuf[myP[k]][s2] = v;
                        }
                    }
                }
            }
            bnd[pw][2*w  ][col] = cur[0];
            bnd[pw][2*w+1][col] = cur[7];
        }

        if ((t & 7) == 7) {                 // receiver flush every 8 steps
            const int o8 = t >> 3;
            __syncthreads();                // recBuf writes of this window visible
            for (int k = tid; k < recCnt*8; k += NTHR) {
                int p = k >> 3, s2 = k & 7;
                y[(size_t)((o8<<3)+s2)*(BB*NREC) + recOut[p]] = recBuf[p][s2];
            }
        }

        if ((t & 15) == 15 && t < NT-1) {   // halo exchange every 16 steps
            const int o16 = t >> 4;
            unsigned long long* G = (unsigned long long*)ws
                                  + (size_t)(o16 & 1) * BNZX;   // ping-pong frames
            // store: entire freshly-valid tile [HALO, REGN-HALO)^2 — with
            // HALO = TILE/2 every cell of it is some neighbor's halo.
            const bool colF = (col >= HALO && col < REGN-HALO);
            #pragma unroll
            for (int m = 0; m < 8; ++m) {
                const int i = r0 + m;
                if (colF && i >= HALO && i < REGN-HALO) {
                    const size_t g = (size_t)b*NZX + (size_t)(oz+i)*NX + gx;
                    __hip_atomic_store(&G[g], pk2(cur[m], prv[m]),
                                       __ATOMIC_RELAXED, __HIP_MEMORY_SCOPE_AGENT);
                }
            }
            grid_sync(flags, (unsigned)(o16 + 1), nbId);
            const bool colH = (col < HALO || col >= REGN-HALO);
            const bool gxIn = (gx >= 0 && gx < NX);
            #pragma unroll
            for (int m = 0; m < 8; ++m) {
                const int i = r0 + m;
                if (colH || i < HALO || i >= REGN-HALO) {
                    const int gz = oz + i;
                    if (gxIn && gz >= 0 && gz < NZ) {
                        unsigned long long v = __hip_atomic_load(
                            &G[(size_t)b*NZX + (size_t)gz*NX + gx],
                            __ATOMIC_RELAXED, __HIP_MEMORY_SCOPE_AGENT);
                        upk2(v, cur[m], prv[m]);
                    } else { cur[m] = 0.f; prv[m] = 0.f; }
                }
            }
            bnd[pw][2*w  ][col] = cur[0];
            bnd[pw][2*w+1][col] = cur[7];
        }
        __syncthreads();
    }
}

extern "C" void kernel_launch(void* const* d_in, const int* in_sizes, int n_in,
                              void* d_out, int out_size, void* d_ws, size_t ws_size,
                              hipStream_t stream) {
    const float* x     = (const float*)d_in[0];
    const float* vp    = (const float*)d_in[1];
    const int*   src_y = (const int*)d_in[2];
    const int*   src_x = (const int*)d_in[3];
    const int*   rec_y = (const int*)d_in[4];
    const int*   rec_x = (const int*)d_in[5];
    float* y  = (float*)d_out;
    float* ws = (float*)d_ws;   // 2 packed frames (4*BNZX floats) + 576*16 flag words

    wave_init<<<(NBLK*FSTRIDE + 255)/256, 256, 0, stream>>>((unsigned*)(ws + 4*BNZX));
    wave_tiled<<<NBLK, NTHR, 0, stream>>>(ws, vp, x, src_y, src_x, rec_y, rec_x, y);
}

// Round 3
// 378.287 us; speedup vs baseline: 1.0566x; 1.0566x over previous
//
#include <hip/hip_runtime.h>

#define BB 4
#define NT 256
#define NZ 384
#define NX 384
#define NREC 128
#define NZX (NZ*NX)        // 147456
#define BNZX (BB*NZX)      // 589824
#define DT 0.001f
#define INV_DH2 0.01f      // 1/(10*10)

#define HALO 16            // halo width = steps per exchange window
#define TILE_R 32          // owned rows per tile
#define TILE_C 96          // owned cols per tile
#define REGN_R 64          // 8 waves x 8 rows
#define REGN_C 128         // 64 lanes x 2 cols
#define NTD_R 12           // 384/32
#define NTD_C 4            // 384/96
#define TPB   48           // tiles per batch
#define NBLK  192          // 48 x 4 batches -> 1 block/CU (64 CUs idle, fine)
#define NTHR  512          // 8 waves
#define FSTRIDE 16         // flag spread (64 B)

__global__ void wave_init(unsigned* flags) {
    int i = blockIdx.x * blockDim.x + threadIdx.x;
    if (i < NBLK * FSTRIDE) flags[i] = 0u;
}

// DPP wave shifts: wave_shr1 -> lane n gets lane n-1, wave_shl1 -> lane n
// gets lane n+1; out-of-range lanes get 0 (bound_ctrl=true).
__device__ inline float dpp_shl1(float v) {
    return __int_as_float(__builtin_amdgcn_update_dpp(
        0, __float_as_int(v), 0x130 /*WAVE_SHL1*/, 0xf, 0xf, true));
}
__device__ inline float dpp_shr1(float v) {
    return __int_as_float(__builtin_amdgcn_update_dpp(
        0, __float_as_int(v), 0x138 /*WAVE_SHR1*/, 0xf, 0xf, true));
}

__device__ inline unsigned long long pk2(float a, float b) {
    union { float f[2]; unsigned long long u; } t; t.f[0] = a; t.f[1] = b; return t.u;
}
__device__ inline void upk2(unsigned long long v, float& a, float& b) {
    union { unsigned long long u; float f[2]; } t; t.u = v; a = t.f[0]; b = t.f[1];
}

__global__ __launch_bounds__(NTHR)
void wave_tiled(float* __restrict__ ws, const float* __restrict__ vp,
                const float* __restrict__ x,
                const int* __restrict__ src_y, const int* __restrict__ src_x,
                const int* __restrict__ rec_y, const int* __restrict__ rec_x,
                float* __restrict__ y) {
    __shared__ float2 bnd[2][16][64];    // [parity][2*wave+{top,bot}][lane] (a,b)
    __shared__ float recBuf[NREC][8];
    __shared__ float xs[NT];
    __shared__ int recLoc[NREC], recOut[NREC];
    __shared__ int recCnt;

    unsigned* flags = (unsigned*)(ws + 4*BNZX);

    const int tid = threadIdx.x;
    const int col = tid & 63;            // lane = col-pair index
    const int w   = tid >> 6;
    const int r0  = w << 3;
    const int blk = blockIdx.x;
    const int b   = blk / TPB;
    const int rem = blk - b*TPB;
    const int tz  = rem >> 2;            // 0..11
    const int tx  = rem & 3;             // 0..3
    const int oz  = tz*TILE_R - HALO;
    const int ox  = tx*TILE_C - HALO;
    const int gx0 = ox + 2*col;          // even global col of this lane
    const int sy = src_y[b], sx = src_x[b];

    if (tid == 0) recCnt = 0;
    for (int k = tid; k < 2*16*64*2; k += NTHR) ((float*)bnd)[k] = 0.f;
    for (int k = tid; k < NT; k += NTHR) xs[k] = x[b*NT + k];
    __syncthreads();
    for (int r = tid; r < NREC; r += NTHR) {
        int ry = rec_y[r], rx = rec_x[r];
        if (ry/TILE_R == tz && rx/TILE_C == tx) {
            int p = atomicAdd(&recCnt, 1);
            recLoc[p] = ((ry - oz) << 8) | (rx - ox);   // row<<8 | region-col
            recOut[p] = b*NREC + r;
        }
    }
    __syncthreads();

    // per-thread receiver ownership cache (cap 4, LDS-loop fallback)
    int myN = 0, myS[4], myP[4];         // myS = m | (half<<3)
    bool ovf = false;
    for (int p = 0; p < recCnt; ++p) {
        int rl = recLoc[p], rc = rl & 255;
        if ((rc >> 1) == col) {
            int rm = (rl >> 8) - r0;
            if ((unsigned)rm < 8u) {
                if (myN < 4) { myS[myN] = rm | ((rc & 1) << 3); myP[myN] = p; ++myN; }
                else ovf = true;
            }
        }
    }

    // neighbor ids for the sync (lanes 0..7 of wave 0; others self)
    int nbId = blk;
    if (tid < 8) {
        int d = tid + (tid >= 4);        // 0..8 skipping center 4
        int nz2 = tz + d/3 - 1, nx2 = tx + d%3 - 1;
        if ((unsigned)nz2 < (unsigned)NTD_R && (unsigned)nx2 < (unsigned)NTD_C)
            nbId = b*TPB + nz2*NTD_C + nx2;
    }

    // per-thread state: 8 rows x 2 cols (a=even col, b=odd col)
    float cxa[8], cxb[8], pxa[8], pxb[8], ca[8], cb[8];
    #pragma unroll
    for (int m = 0; m < 8; ++m) {
        cxa[m] = cxb[m] = pxa[m] = pxb[m] = 0.f;
        const int gz = oz + r0 + m;
        const bool giz = (gz > 0 && gz < NZ-1);
        const float va = (giz && gx0 > 0 && gx0 < NX-1)    ? vp[gz*NX + gx0]   * DT : 0.f;
        const float vb = (giz && gx0 >= 0 && gx0+1 < NX-1) ? vp[gz*NX + gx0+1] * DT : 0.f;
        ca[m] = va * va * INV_DH2;       // 0 at edges -> lap auto-masked
        cb[m] = vb * vb * INV_DH2;
    }
    const int  scol  = sx - ox;
    const bool srcLn = ((unsigned)scol < (unsigned)REGN_C) && ((scol >> 1) == col);
    const bool srcB  = srcLn && (scol & 1);
    const bool srcA  = srcLn && !(scol & 1);
    const int  srcM  = sy - oz - r0;
    const int  iuUp  = (2*w-1 < 0) ? 0 : 2*w-1;
    const int  iuDn  = (2*w+2 > 15) ? 15 : 2*w+2;
    __syncthreads();

    #pragma unroll 1
    for (int t = 0; t < NT; ++t) {
        const int pr = t & 1, pw = pr ^ 1;
        const float2 upB = bnd[pr][iuUp][col];
        const float2 dnB = bnd[pr][iuDn][col];

        float na[8], nb[8];
        #pragma unroll
        for (int m = 0; m < 8; ++m) {
            const float cea = cxa[m], ceb = cxb[m];
            const float upa = (m == 0) ? upB.x : cxa[m-1];
            const float upb = (m == 0) ? upB.y : cxb[m-1];
            const float dna = (m == 7) ? dnB.x : cxa[m+1];
            const float dnb = (m == 7) ? dnB.y : cxb[m+1];
            const float lfa = dpp_shr1(ceb);   // col 2j-1 (lane j-1's b)
            const float rtb = dpp_shl1(cea);   // col 2j+2 (lane j+1's a)
            const float sa = (upa + dna) + (lfa + ceb);
            const float sb = (upb + dnb) + (cea + rtb);
            na[m] = fmaf(2.f, cea, -pxa[m]) + ca[m] * fmaf(-4.f, cea, sa);
            nb[m] = fmaf(2.f, ceb, -pxb[m]) + cb[m] * fmaf(-4.f, ceb, sb);
        }
        #pragma unroll
        for (int m = 0; m < 8; ++m) {
            pxa[m] = cxa[m]; cxa[m] = na[m];
            pxb[m] = cxb[m]; cxb[m] = nb[m];
        }

        if ((srcA || srcB) && (unsigned)srcM < 8u) {
            const float xv = xs[t];
            #pragma unroll
            for (int m = 0; m < 8; ++m) if (m == srcM) {
                if (srcA) cxa[m] += xv; else cxb[m] += xv;
            }
        }
        // receiver sampling -> LDS buffer
        {
            const int s2 = t & 7;
            if (ovf) {
                for (int p = 0; p < recCnt; ++p) {
                    int rl = recLoc[p], rc = rl & 255;
                    if ((rc >> 1) == col) {
                        int rm = (rl >> 8) - r0;
                        if ((unsigned)rm < 8u) {
                            float v = (rc & 1) ? cxb[0] : cxa[0];
                            #pragma unroll
                            for (int m = 1; m < 8; ++m)
                                if (rm == m) v = (rc & 1) ? cxb[m] : cxa[m];
                            recBuf[p][s2] = v;
                        }
                    }
                }
            } else {
                #pragma unroll
                for (int k = 0; k < 4; ++k) {
                    if (k < myN) {
                        const int rm = myS[k] & 7, hf = myS[k] >> 3;
                        float v = hf ? cxb[0] : cxa[0];
                        #pragma unroll
                        for (int m = 1; m < 8; ++m)
                            if (rm == m) v = hf ? cxb[m] : cxa[m];
                        recBuf[myP[k]][s2] = v;
                    }
                }
            }
        }
        bnd[pw][2*w  ][col] = make_float2(cxa[0], cxb[0]);
        bnd[pw][2*w+1][col] = make_float2(cxa[7], cxb[7]);

        if ((t & 7) == 7) {
            const int o8 = t >> 3;
            const bool exch = ((t & 15) == 15) && (t < NT-1);
            unsigned long long* G = nullptr;
            if (exch) {
                G = (unsigned long long*)ws + (size_t)((t >> 4) & 1) * BNZX;
                // store entire freshly-valid interior [HALO,REGN-HALO)^2:
                // rows all needed by up/down (TILE_R == 2*HALO), cols by l/r.
                const bool colS = (col >= 8 && col < 56);   // region cols [16,112)
                #pragma unroll
                for (int m = 0; m < 8; ++m) {
                    const int i = r0 + m;
                    if (colS && i >= HALO && i < REGN_R-HALO) {
                        const size_t g = (size_t)b*NZX + (size_t)(oz+i)*NX + gx0;
                        __hip_atomic_store(&G[g],   pk2(cxa[m], pxa[m]),
                                           __ATOMIC_RELAXED, __HIP_MEMORY_SCOPE_AGENT);
                        __hip_atomic_store(&G[g+1], pk2(cxb[m], pxb[m]),
                                           __ATOMIC_RELAXED, __HIP_MEMORY_SCOPE_AGENT);
                    }
                }
            }
            __syncthreads();   // recBuf visible; drains vmcnt -> frame at LLC
            if (exch && tid == 0)
                __hip_atomic_store(&flags[blk * FSTRIDE], (unsigned)((t >> 4) + 1),
                                   __ATOMIC_RELAXED, __HIP_MEMORY_SCOPE_AGENT);
            // receiver flush overlaps the neighbor wait
            for (int k = tid; k < recCnt*8; k += NTHR) {
                int p = k >> 3, q = k & 7;
                y[(size_t)((o8 << 3) + q)*(BB*NREC) + recOut[p]] = recBuf[p][q];
            }
            if (exch) {
                const unsigned gen = (unsigned)((t >> 4) + 1);
                if (tid < 64) {
                    for (;;) {
                        unsigned f = __hip_atomic_load(&flags[nbId * FSTRIDE],
                                         __ATOMIC_RELAXED, __HIP_MEMORY_SCOPE_AGENT);
                        if (__all(f >= gen)) break;
                        __builtin_amdgcn_s_sleep(1);
                    }
                }
                __syncthreads();
                const bool colH = (col < 8 || col >= 56);
                #pragma unroll
                for (int m = 0; m < 8; ++m) {
                    const int i = r0 + m;
                    if (colH || i < HALO || i >= REGN_R-HALO) {
                        const int gz = oz + i;
                        const size_t gr = (size_t)b*NZX + (size_t)gz*NX;
                        // guards: BOTH bounds per half (gx0 can be <0 on tx=0
                        // edge tiles and >=NX on tx=3 edge tiles; missing
                        // bounds here caused the round-2 memory fault).
                        if (gz >= 0 && gz < NZ && gx0 >= 0 && gx0 < NX) {
                            upk2(__hip_atomic_load(&G[gr + gx0],
                                     __ATOMIC_RELAXED, __HIP_MEMORY_SCOPE_AGENT),
                                 cxa[m], pxa[m]);
                        } else { cxa[m] = 0.f; pxa[m] = 0.f; }
                        if (gz >= 0 && gz < NZ && gx0+1 >= 0 && gx0+1 < NX) {
                            upk2(__hip_atomic_load(&G[gr + gx0 + 1],
                                     __ATOMIC_RELAXED, __HIP_MEMORY_SCOPE_AGENT),
                                 cxb[m], pxb[m]);
                        } else { cxb[m] = 0.f; pxb[m] = 0.f; }
                    }
                }
                bnd[pw][2*w  ][col] = make_float2(cxa[0], cxb[0]);
                bnd[pw][2*w+1][col] = make_float2(cxa[7], cxb[7]);
            }
        }
        __syncthreads();
    }
}

extern "C" void kernel_launch(void* const* d_in, const int* in_sizes, int n_in,
                              void* d_out, int out_size, void* d_ws, size_t ws_size,
                              hipStream_t stream) {
    const float* x     = (const float*)d_in[0];
    const float* vp    = (const float*)d_in[1];
    const int*   src_y = (const int*)d_in[2];
    const int*   src_x = (const int*)d_in[3];
    const int*   rec_y = (const int*)d_in[4];
    const int*   rec_x = (const int*)d_in[5];
    float* y  = (float*)d_out;
    float* ws = (float*)d_ws;   // 2 packed frames (4*BNZX floats) + flags

    wave_init<<<(NBLK*FSTRIDE + 255)/256, 256, 0, stream>>>((unsigned*)(ws + 4*BNZX));
    wave_tiled<<<NBLK, NTHR, 0, stream>>>(ws, vp, x, src_y, src_x, rec_y, rec_x, y);
}

// Round 4
// 328.321 us; speedup vs baseline: 1.2174x; 1.1522x over previous
//
#include <hip/hip_runtime.h>

#define BB 4
#define NT 256
#define NZ 384
#define NX 384
#define NREC 128
#define NZX (NZ*NX)        // 147456
#define BNZX (BB*NZX)      // 589824
#define DT 0.001f
#define INV_DH2 0.01f      // 1/(10*10)

#define TILE 48            // interior tile edge
#define HALO 8             // halo width = KSTEP
#define REGN 64            // TILE + 2*HALO
#define NBLK 256           // 8x8 tiles x 4 batches (1 block/CU)
#define NTHR 512           // 8 waves: wave w owns rows 8w..8w+7, lane = col
#define FSTRIDE 16         // flag spread (64 B) -> no line sharing

__global__ void wave_init(unsigned* flags) {
    int i = blockIdx.x * blockDim.x + threadIdx.x;
    if (i < NBLK * FSTRIDE) flags[i] = 0u;
}

__device__ inline float dpp_shl1(float v) {
    return __int_as_float(__builtin_amdgcn_update_dpp(
        0, __float_as_int(v), 0x130 /*WAVE_SHL1*/, 0xf, 0xf, true));
}
__device__ inline float dpp_shr1(float v) {
    return __int_as_float(__builtin_amdgcn_update_dpp(
        0, __float_as_int(v), 0x138 /*WAVE_SHR1*/, 0xf, 0xf, true));
}

// (cur,prv) packed into one 8B word: halves sc1 transactions per exchange.
__device__ inline unsigned long long pk2(float a, float b) {
    union { float f[2]; unsigned long long u; } t; t.f[0] = a; t.f[1] = b; return t.u;
}
__device__ inline void upk2(unsigned long long v, float& a, float& b) {
    union { unsigned long long u; float f[2]; } t; t.u = v; a = t.f[0]; b = t.f[1];
}

__global__ __launch_bounds__(NTHR)
void wave_tiled(float* __restrict__ ws, const float* __restrict__ vp,
                const float* __restrict__ x,
                const int* __restrict__ src_y, const int* __restrict__ src_x,
                const int* __restrict__ rec_y, const int* __restrict__ rec_x,
                float* __restrict__ y) {
    __shared__ float bnd[2][16][REGN];   // [parity][2*wave+{top,bot}][col]
    __shared__ float recBuf[NREC][8];    // receiver samples, flushed per window
    __shared__ float xs[NT];             // this batch's source trace
    __shared__ int recLoc[NREC], recOut[NREC];
    __shared__ int recCnt;

    unsigned* flags = (unsigned*)(ws + 4*BNZX);

    const int tid = threadIdx.x;
    const int col = tid & 63;
    const int w   = tid >> 6;
    const int r0  = w << 3;
    const int blk = blockIdx.x;
    const int b  = blk >> 6;
    const int tz = (blk >> 3) & 7;
    const int tx = blk & 7;
    const int oz = tz*TILE - HALO, ox = tx*TILE - HALO;
    const int gx = ox + col;
    const int sy = src_y[b], sx = src_x[b];

    if (tid == 0) recCnt = 0;
    for (int k = tid; k < 16*REGN; k += NTHR) ((float*)bnd[0])[k] = 0.f;
    for (int k = tid; k < NT; k += NTHR) xs[k] = x[b*NT + k];
    __syncthreads();
    for (int r = tid; r < NREC; r += NTHR) {
        int ry = rec_y[r], rx = rec_x[r];
        if (ry/TILE == tz && rx/TILE == tx) {
            int p = atomicAdd(&recCnt, 1);
            recLoc[p] = ((ry - oz) << 6) | (rx - ox);
            recOut[p] = b*NREC + r;
        }
    }
    __syncthreads();

    // per-thread receiver ownership cache (cap 4, LDS-loop fallback)
    int myN = 0, myM[4], myP[4];
    bool ovf = false;
    for (int p = 0; p < recCnt; ++p) {
        int rl = recLoc[p];
        if ((rl & 63) == col) {
            int rm = (rl >> 6) - r0;
            if ((unsigned)rm < 8u) {
                if (myN < 4) { myM[myN] = rm; myP[myN] = p; ++myN; }
                else ovf = true;
            }
        }
    }

    // neighbor ids for the sync (lanes 0..7 of wave 0; others self)
    int nbId = blk;
    if (tid < 8) {
        int d = tid + (tid >= 4);            // 0..8 skipping center 4
        int nz2 = tz + d/3 - 1, nx2 = tx + d%3 - 1;
        if ((unsigned)nz2 < 8u && (unsigned)nx2 < 8u)
            nbId = (b << 6) | (nz2 << 3) | nx2;
    }

    // per-thread column state: 8 rows in registers
    float cur[8], prv[8], c2i[8];
    #pragma unroll
    for (int m = 0; m < 8; ++m) {
        cur[m] = 0.f; prv[m] = 0.f;
        const int gz = oz + r0 + m;
        const bool inner = (gz > 0 && gz < NZ-1 && gx > 0 && gx < NX-1);
        const float v = inner ? vp[gz*NX + gx] * DT : 0.f;
        c2i[m] = v * v * INV_DH2;    // 0 at edges -> lap auto-masked
    }
    const bool srcCol = (gx == sx);
    const int  srcM   = sy - oz - r0;
    const int  iuUp   = (2*w-1 < 0) ? 0 : 2*w-1;
    const int  iuDn   = (2*w+2 > 15) ? 15 : 2*w+2;
    __syncthreads();

    #pragma unroll 1
    for (int t = 0; t < NT; ++t) {
        const int pr = t & 1, pw = pr ^ 1;
        const float upB = bnd[pr][iuUp][col];
        const float dnB = bnd[pr][iuDn][col];

        float hn[8];
        #pragma unroll
        for (int m = 0; m < 8; ++m) {
            const float ce = cur[m];
            const float up = (m == 0) ? upB : cur[m-1];
            const float dn = (m == 7) ? dnB : cur[m+1];
            const float lf = dpp_shl1(ce);
            const float rt = dpp_shr1(ce);
            const float s  = (up + dn) + (lf + rt);
            hn[m] = fmaf(2.f, ce, -prv[m]) + c2i[m] * fmaf(-4.f, ce, s);
        }
        #pragma unroll
        for (int m = 0; m < 8; ++m) { prv[m] = cur[m]; cur[m] = hn[m]; }

        if (srcCol && (unsigned)srcM < 8u) {
            const float xv = xs[t];
            #pragma unroll
            for (int m = 0; m < 8; ++m) if (m == srcM) cur[m] += xv;
        }
        // receiver sampling -> LDS buffer (no global ops in the step loop)
        {
            const int s2 = t & 7;
            if (ovf) {
                for (int p = 0; p < recCnt; ++p) {
                    int rl = recLoc[p];
                    if ((rl & 63) == col) {
                        int rm = (rl >> 6) - r0;
                        if ((unsigned)rm < 8u) {
                            float v = cur[0];
                            #pragma unroll
                            for (int m = 1; m < 8; ++m) if (rm == m) v = cur[m];
                            recBuf[p][s2] = v;
                        }
                    }
                }
            } else {
                #pragma unroll
                for (int k = 0; k < 4; ++k) {
                    if (k < myN) {
                        float v = cur[0];
                        #pragma unroll
                        for (int m = 1; m < 8; ++m) if (myM[k] == m) v = cur[m];
                        recBuf[myP[k]][s2] = v;
                    }
                }
            }
        }
        bnd[pw][2*w  ][col] = cur[0];
        bnd[pw][2*w+1][col] = cur[7];

        if ((t & 7) == 7) {
            const int o = t >> 3;
            const bool exch = (t < NT-1);
            unsigned long long* G = nullptr;
            if (exch) {
                G = (unsigned long long*)ws + (size_t)(o & 1) * BNZX;  // ping-pong
                // store the ring between depth HALO and 2*HALO (what any
                // neighbor can need as halo); always in-domain for edge tiles.
                const bool colF = (col >= HALO   && col < REGN-HALO);
                const bool colM = (col >= 2*HALO && col < REGN-2*HALO);
                #pragma unroll
                for (int m = 0; m < 8; ++m) {
                    const int i = r0 + m;
                    const bool rowF = (i >= HALO   && i < REGN-HALO);
                    const bool rowM = (i >= 2*HALO && i < REGN-2*HALO);
                    if (colF && rowF && !(colM && rowM)) {
                        const size_t g = (size_t)b*NZX + (size_t)(oz+i)*NX + gx;
                        __hip_atomic_store(&G[g], pk2(cur[m], prv[m]),
                                           __ATOMIC_RELAXED, __HIP_MEMORY_SCOPE_AGENT);
                    }
                }
            }
            __syncthreads();   // recBuf visible; drains vmcnt -> frame at LLC
            // post arrival BEFORE the y-flush: flag chain no longer waits on y
            if (exch && tid == 0)
                __hip_atomic_store(&flags[blk * FSTRIDE], (unsigned)(o + 1),
                                   __ATOMIC_RELAXED, __HIP_MEMORY_SCOPE_AGENT);
            // receiver flush overlaps the neighbor wait
            for (int k = tid; k < recCnt*8; k += NTHR) {
                int p = k >> 3, s2 = k & 7;
                y[(size_t)((o<<3)+s2)*(BB*NREC) + recOut[p]] = recBuf[p][s2];
            }
            if (exch) {
                const unsigned gen = (unsigned)(o + 1);
                if (tid < 64) {
                    for (;;) {
                        unsigned f = __hip_atomic_load(&flags[nbId * FSTRIDE],
                                         __ATOMIC_RELAXED, __HIP_MEMORY_SCOPE_AGENT);
                        if (__all(f >= gen)) break;
                        __builtin_amdgcn_s_sleep(1);
                    }
                }
                __syncthreads();
                const bool colH = (col < HALO || col >= REGN-HALO);
                const bool gxIn = (gx >= 0 && gx < NX);
                #pragma unroll
                for (int m = 0; m < 8; ++m) {
                    const int i = r0 + m;
                    if (colH || i < HALO || i >= REGN-HALO) {
                        const int gz = oz + i;
                        if (gxIn && gz >= 0 && gz < NZ) {
                            unsigned long long v = __hip_atomic_load(
                                &G[(size_t)b*NZX + (size_t)gz*NX + gx],
                                __ATOMIC_RELAXED, __HIP_MEMORY_SCOPE_AGENT);
                            upk2(v, cur[m], prv[m]);
                        } else { cur[m] = 0.f; prv[m] = 0.f; }
                    }
                }
                bnd[pw][2*w  ][col] = cur[0];
                bnd[pw][2*w+1][col] = cur[7];
            }
        }
        __syncthreads();
    }
}

extern "C" void kernel_launch(void* const* d_in, const int* in_sizes, int n_in,
                              void* d_out, int out_size, void* d_ws, size_t ws_size,
                              hipStream_t stream) {
    const float* x     = (const float*)d_in[0];
    const float* vp    = (const float*)d_in[1];
    const int*   src_y = (const int*)d_in[2];
    const int*   src_x = (const int*)d_in[3];
    const int*   rec_y = (const int*)d_in[4];
    const int*   rec_x = (const int*)d_in[5];
    float* y  = (float*)d_out;
    float* ws = (float*)d_ws;   // 2 packed u64 frames (== 4*BNZX floats) + flags

    wave_init<<<(NBLK*FSTRIDE + 255)/256, 256, 0, stream>>>((unsigned*)(ws + 4*BNZX));
    wave_tiled<<<NBLK, NTHR, 0, stream>>>(ws, vp, x, src_y, src_x, rec_y, rec_x, y);
}